// Round 3
// baseline (510.864 us; speedup 1.0000x reference)
//
#include <hip/hip_runtime.h>

#define NTOK 4096
#define KK   3276   // int(4096 * 0.8)

__device__ __forceinline__ unsigned key_of(float f) {
    unsigned u = __float_as_uint(f);
    return (u & 0x80000000u) ? ~u : (u | 0x80000000u);
}
__device__ __forceinline__ float float_of_key(unsigned k) {
    unsigned u = (k & 0x80000000u) ? (k ^ 0x80000000u) : ~k;
    return __uint_as_float(u);
}

// Fused: pointwise-over-t conv + depthwise 3x3 + scatter to [head][n][4] + sum-of-squares
// One block per (o,c) plane: o in [0,12), c in [0,32).
__global__ __launch_bounds__(256) void k_fused(const float* __restrict__ x,
                                               const float* __restrict__ wq,
                                               const float* __restrict__ wdw,
                                               float* __restrict__ qh,
                                               float* __restrict__ kh,
                                               float* __restrict__ vh,
                                               float* __restrict__ ss) {
    __shared__ float p[1024];
    int b = blockIdx.x;
    int o = b >> 5, c = b & 31;
    int tid = threadIdx.x;
    float w0 = wq[o * 4 + 0], w1 = wq[o * 4 + 1], w2 = wq[o * 4 + 2], w3 = wq[o * 4 + 3];
    const float* x0 = x + (c << 10);
    #pragma unroll
    for (int r = 0; r < 4; ++r) {
        int hw = tid + (r << 8);
        float a = w0 * x0[hw];
        a = fmaf(w1, x0[(32 << 10) + hw], a);
        a = fmaf(w2, x0[(64 << 10) + hw], a);
        a = fmaf(w3, x0[(96 << 10) + hw], a);
        p[hw] = a;
    }
    __syncthreads();
    float wd[9];
    #pragma unroll
    for (int i = 0; i < 9; ++i) wd[i] = wdw[o * 9 + i];
    int g = o >> 2, t = o & 3;
    int head = c >> 2, cph = c & 3;
    float* dst = (g == 0) ? qh : (g == 1) ? kh : vh;
    float ssum = 0.f;
    #pragma unroll
    for (int r = 0; r < 4; ++r) {
        int hw = tid + (r << 8);
        int wcol = hw & 31, hrow = hw >> 5;
        float a = 0.f;
        #pragma unroll
        for (int dy = -1; dy <= 1; ++dy) {
            int hh = hrow + dy;
            if (hh < 0 || hh > 31) continue;
            #pragma unroll
            for (int dx = -1; dx <= 1; ++dx) {
                int ww = wcol + dx;
                if (ww < 0 || ww > 31) continue;
                a = fmaf(wd[(dy + 1) * 3 + (dx + 1)], p[hh * 32 + ww], a);
            }
        }
        int n = (hw << 2) + t;
        dst[(((head << 12) + n) << 2) + cph] = a;
        ssum = fmaf(a, a, ssum);
    }
    if (g < 2) {
        #pragma unroll
        for (int off = 32; off > 0; off >>= 1) ssum += __shfl_down(ssum, off, 64);
        if ((tid & 63) == 0) atomicAdd(&ss[g * 32 + c], ssum);
    }
}

// One block per (head, row n). 6 barriers total; scans are per-wave (redundant, conflict-free).
__global__ __launch_bounds__(256) void k_attn(const float* __restrict__ qh,
                                              const float* __restrict__ kh,
                                              const float* __restrict__ vh,
                                              const float* __restrict__ ss,
                                              const float* __restrict__ temp,
                                              float* __restrict__ outp) {
    __shared__ unsigned hist[4][256];
    __shared__ float red[44];

    int bid = blockIdx.x;
    int head = bid >> 12;
    int n = bid & 4095;
    int tid = threadIdx.x;
    int lane = tid & 63;

    // clear all 4 histograms once
    unsigned* hb = &hist[0][0];
    hb[tid] = 0; hb[256 + tid] = 0; hb[512 + tid] = 0; hb[768 + tid] = 0;

    // per-cph combined scale: temp * (1/max(||q_c||,eps)) * (1/max(||k_c||,eps))
    float tempv = temp[head];
    const float* sq = ss + head * 4;
    const float* sk = ss + 32 + head * 4;
    float f0 = tempv / (fmaxf(sqrtf(sq[0]), 1e-12f) * fmaxf(sqrtf(sk[0]), 1e-12f));
    float f1 = tempv / (fmaxf(sqrtf(sq[1]), 1e-12f) * fmaxf(sqrtf(sk[1]), 1e-12f));
    float f2 = tempv / (fmaxf(sqrtf(sq[2]), 1e-12f) * fmaxf(sqrtf(sk[2]), 1e-12f));
    float f3 = tempv / (fmaxf(sqrtf(sq[3]), 1e-12f) * fmaxf(sqrtf(sk[3]), 1e-12f));
    float M = fabsf(tempv);          // |score| <= |temp| since |q^.k^| <= 1

    const float4* kb4 = (const float4*)kh + (head << 12);
    const float4* vb4 = (const float4*)vh + (head << 12);
    float4 qv = ((const float4*)qh)[(head << 12) + n];
    qv.x *= f0; qv.y *= f1; qv.z *= f2; qv.w *= f3;

    __syncthreads();                                   // (1) clears visible

    // Phase 1: scores -> keys in regs, fused pass-0 histogram
    unsigned keys[16];
    #pragma unroll
    for (int j = 0; j < 16; ++j) {
        int m = tid + (j << 8);
        float4 kv = kb4[m];
        float val = qv.x * kv.x;
        val = fmaf(qv.y, kv.y, val);
        val = fmaf(qv.z, kv.z, val);
        val = fmaf(qv.w, kv.w, val);
        unsigned key = key_of(val);
        keys[j] = key;
        atomicAdd(&hist[0][key >> 24], 1u);
    }

    unsigned need = KK;
    unsigned prefix = 0;   // grows 8 bits per pass

    #pragma unroll
    for (int pass = 0; pass < 4; ++pass) {
        __syncthreads();                               // (2..5) pass-p atomics done
        // per-wave suffix scan of hist[pass] (256 bins, 4 chunks of 64)
        unsigned c0 = hist[pass][lane];
        unsigned c1 = hist[pass][64 + lane];
        unsigned c2 = hist[pass][128 + lane];
        unsigned c3 = hist[pass][192 + lane];
        unsigned s0 = c0, s1 = c1, s2 = c2, s3 = c3;
        #pragma unroll
        for (int off = 1; off < 64; off <<= 1) {
            unsigned v0 = __shfl_down(s0, off, 64);
            unsigned v1 = __shfl_down(s1, off, 64);
            unsigned v2 = __shfl_down(s2, off, 64);
            unsigned v3 = __shfl_down(s3, off, 64);
            if (lane + off < 64) { s0 += v0; s1 += v1; s2 += v2; s3 += v3; }
        }
        unsigned t1 = __shfl(s1, 0, 64), t2 = __shfl(s2, 0, 64), t3 = __shfl(s3, 0, 64);
        unsigned S0 = s0 + t1 + t2 + t3;
        unsigned S1 = s1 + t2 + t3;
        unsigned S2 = s2 + t3;
        unsigned S3 = s3;
        unsigned digL = 0, needL = 0;
        bool found = false;
        if (S0 >= need && S0 - c0 < need) { digL = lane;        needL = need - (S0 - c0); found = true; }
        if (S1 >= need && S1 - c1 < need) { digL = 64 + lane;   needL = need - (S1 - c1); found = true; }
        if (S2 >= need && S2 - c2 < need) { digL = 128 + lane;  needL = need - (S2 - c2); found = true; }
        if (S3 >= need && S3 - c3 < need) { digL = 192 + lane;  needL = need - (S3 - c3); found = true; }
        unsigned long long mk = __ballot(found);
        int src = __builtin_ctzll(mk);
        unsigned dig = __shfl((int)digL, src, 64);
        need = __shfl((int)needL, src, 64);
        prefix = (prefix << 8) | dig;

        // next pass atomics (prefix-compare, no mask bookkeeping)
        if (pass == 0) {
            #pragma unroll
            for (int j = 0; j < 16; ++j)
                if ((keys[j] >> 24) == prefix) atomicAdd(&hist[1][(keys[j] >> 16) & 255u], 1u);
        } else if (pass == 1) {
            #pragma unroll
            for (int j = 0; j < 16; ++j)
                if ((keys[j] >> 16) == prefix) atomicAdd(&hist[2][(keys[j] >> 8) & 255u], 1u);
        } else if (pass == 2) {
            #pragma unroll
            for (int j = 0; j < 16; ++j)
                if ((keys[j] >> 8) == prefix) atomicAdd(&hist[3][keys[j] & 255u], 1u);
        }
    }
    unsigned tau = prefix;
    unsigned needEq = need;

    // Phase 3: masked softmax + PV with tie accumulators
    float denom = 0.f, a0 = 0.f, a1 = 0.f, a2 = 0.f, a3 = 0.f;
    float de = 0.f, e0 = 0.f, e1 = 0.f, e2 = 0.f, e3 = 0.f;
    float cntf = 0.f;
    #pragma unroll
    for (int j = 0; j < 16; ++j) {
        unsigned key = keys[j];
        if (key < tau) continue;
        int m = tid + (j << 8);
        float sv = float_of_key(key);
        float w = __expf(sv - M);
        float4 vv = vb4[m];
        if (key == tau) {
            cntf += 1.f; de += w;
            e0 = fmaf(w, vv.x, e0); e1 = fmaf(w, vv.y, e1);
            e2 = fmaf(w, vv.z, e2); e3 = fmaf(w, vv.w, e3);
        } else {
            denom += w;
            a0 = fmaf(w, vv.x, a0); a1 = fmaf(w, vv.y, a1);
            a2 = fmaf(w, vv.z, a2); a3 = fmaf(w, vv.w, a3);
        }
    }
    #pragma unroll
    for (int off = 32; off > 0; off >>= 1) {
        denom += __shfl_down(denom, off, 64);
        a0 += __shfl_down(a0, off, 64); a1 += __shfl_down(a1, off, 64);
        a2 += __shfl_down(a2, off, 64); a3 += __shfl_down(a3, off, 64);
        de += __shfl_down(de, off, 64);
        e0 += __shfl_down(e0, off, 64); e1 += __shfl_down(e1, off, 64);
        e2 += __shfl_down(e2, off, 64); e3 += __shfl_down(e3, off, 64);
        cntf += __shfl_down(cntf, off, 64);
    }
    if ((tid & 63) == 0) {
        float* r = red + (tid >> 6) * 11;
        r[0] = denom; r[1] = a0; r[2] = a1; r[3] = a2; r[4] = a3;
        r[5] = de; r[6] = e0; r[7] = e1; r[8] = e2; r[9] = e3; r[10] = cntf;
    }
    __syncthreads();                                   // (6)
    if (tid == 0) {
        float rD = 0, r0 = 0, r1 = 0, r2 = 0, r3 = 0;
        float qD = 0, q0 = 0, q1 = 0, q2 = 0, q3 = 0, qc = 0;
        #pragma unroll
        for (int w = 0; w < 4; ++w) {
            float* r = red + w * 11;
            rD += r[0]; r0 += r[1]; r1 += r[2]; r2 += r[3]; r3 += r[4];
            qD += r[5]; q0 += r[6]; q1 += r[7]; q2 += r[8]; q3 += r[9]; qc += r[10];
        }
        float scaleEq = (float)needEq / qc;
        float D = rD + scaleEq * qD;
        float invD = 1.f / D;
        outp[((head << 2) + 0) * NTOK + n] = (r0 + scaleEq * q0) * invD;
        outp[((head << 2) + 1) * NTOK + n] = (r1 + scaleEq * q1) * invD;
        outp[((head << 2) + 2) * NTOK + n] = (r2 + scaleEq * q2) * invD;
        outp[((head << 2) + 3) * NTOK + n] = (r3 + scaleEq * q3) * invD;
    }
}

// out[o][p] = sum_ch wp[o][ch] * ao[head(ch)*4+cph(ch)][p*4 + t(ch)], ch = t*32 + head*4 + cph
__global__ void k_proj(const float* __restrict__ ao, const float* __restrict__ wp,
                       float* __restrict__ out) {
    __shared__ float chin[128];
    int p = blockIdx.x;
    int tid = threadIdx.x;       // 128
    int t = tid >> 5;
    int c = tid & 31;
    chin[tid] = ao[c * NTOK + (p << 2) + t];
    __syncthreads();
    const float* wr = wp + tid * 128;
    float acc = 0.f;
    #pragma unroll 8
    for (int ch = 0; ch < 128; ++ch) acc = fmaf(wr[ch], chin[ch], acc);
    out[tid * 1024 + p] = acc;
}

extern "C" void kernel_launch(void* const* d_in, const int* in_sizes, int n_in,
                              void* d_out, int out_size, void* d_ws, size_t ws_size,
                              hipStream_t stream) {
    const float* x    = (const float*)d_in[0];
    const float* temp = (const float*)d_in[1];
    const float* wq   = (const float*)d_in[2];
    const float* wdw  = (const float*)d_in[3];
    const float* wp   = (const float*)d_in[4];
    float* out = (float*)d_out;
    float* ws = (float*)d_ws;

    float* qh = ws;                      // [head][n][4] = 131072 floats
    float* kh = qh + 131072;
    float* vh = kh + 131072;
    float* ao = vh + 131072;             // [c][n]
    float* ssb = ao + 131072;            // [2][8][4] = 64 floats

    hipMemsetAsync(ssb, 0, 64 * sizeof(float), stream);
    k_fused<<<384,   256, 0, stream>>>(x, wq, wdw, qh, kh, vh, ssb);
    k_attn <<<32768, 256, 0, stream>>>(qh, kh, vh, ssb, temp, ao);
    k_proj <<<1024,  128, 0, stream>>>(ao, wp, out);
}

// Round 4
// 486.054 us; speedup vs baseline: 1.0510x; 1.0510x over previous
//
#include <hip/hip_runtime.h>

#define NTOK 4096
#define KK   3276   // int(4096 * 0.8)
#define RT   4      // rows (q tokens) per block

__device__ __forceinline__ unsigned key_of(float f) {
    unsigned u = __float_as_uint(f);
    return (u & 0x80000000u) ? ~u : (u | 0x80000000u);
}
__device__ __forceinline__ float float_of_key(unsigned k) {
    unsigned u = (k & 0x80000000u) ? (k ^ 0x80000000u) : ~k;
    return __uint_as_float(u);
}

// Fused: pointwise-over-t conv + depthwise 3x3 + scatter to [head][n][4] + sum-of-squares
__global__ __launch_bounds__(256) void k_fused(const float* __restrict__ x,
                                               const float* __restrict__ wq,
                                               const float* __restrict__ wdw,
                                               float* __restrict__ qh,
                                               float* __restrict__ kh,
                                               float* __restrict__ vh,
                                               float* __restrict__ ss) {
    __shared__ float p[1024];
    int b = blockIdx.x;
    int o = b >> 5, c = b & 31;
    int tid = threadIdx.x;
    float w0 = wq[o * 4 + 0], w1 = wq[o * 4 + 1], w2 = wq[o * 4 + 2], w3 = wq[o * 4 + 3];
    const float* x0 = x + (c << 10);
    #pragma unroll
    for (int r = 0; r < 4; ++r) {
        int hw = tid + (r << 8);
        float a = w0 * x0[hw];
        a = fmaf(w1, x0[(32 << 10) + hw], a);
        a = fmaf(w2, x0[(64 << 10) + hw], a);
        a = fmaf(w3, x0[(96 << 10) + hw], a);
        p[hw] = a;
    }
    __syncthreads();
    float wd[9];
    #pragma unroll
    for (int i = 0; i < 9; ++i) wd[i] = wdw[o * 9 + i];
    int g = o >> 2, t = o & 3;
    int head = c >> 2, cph = c & 3;
    float* dst = (g == 0) ? qh : (g == 1) ? kh : vh;
    float ssum = 0.f;
    #pragma unroll
    for (int r = 0; r < 4; ++r) {
        int hw = tid + (r << 8);
        int wcol = hw & 31, hrow = hw >> 5;
        float a = 0.f;
        #pragma unroll
        for (int dy = -1; dy <= 1; ++dy) {
            int hh = hrow + dy;
            if (hh < 0 || hh > 31) continue;
            #pragma unroll
            for (int dx = -1; dx <= 1; ++dx) {
                int ww = wcol + dx;
                if (ww < 0 || ww > 31) continue;
                a = fmaf(wd[(dy + 1) * 3 + (dx + 1)], p[hh * 32 + ww], a);
            }
        }
        int n = (hw << 2) + t;
        dst[(((head << 12) + n) << 2) + cph] = a;
        ssum = fmaf(a, a, ssum);
    }
    if (g < 2) {
        #pragma unroll
        for (int off = 32; off > 0; off >>= 1) ssum += __shfl_down(ssum, off, 64);
        if ((tid & 63) == 0) atomicAdd(&ss[g * 32 + c], ssum);
    }
}

// One block per (head, 4 consecutive rows). Keys for all 4 rows in registers.
__global__ __launch_bounds__(256, 2) void k_attn(const float* __restrict__ qh,
                                                 const float* __restrict__ kh,
                                                 const float* __restrict__ vh,
                                                 const float* __restrict__ ss,
                                                 const float* __restrict__ temp,
                                                 float* __restrict__ outp) {
    __shared__ unsigned hist[4][RT][256];     // 16 KB: [pass][row][bin]
    __shared__ float red[4][RT][5];
    __shared__ unsigned cnt_red[4][RT];

    int bid = blockIdx.x;
    int head = bid >> 10;
    int n0 = (bid & 1023) << 2;
    int tid = threadIdx.x;
    int lane = tid & 63;
    int wv = tid >> 6;

    // clear all histograms (4096 u32)
    unsigned* hb = &hist[0][0][0];
    #pragma unroll
    for (int i = 0; i < 16; ++i) hb[tid + (i << 8)] = 0;

    // per-cph combined scale (uniform)
    float tempv = temp[head];
    const float* sq = ss + head * 4;
    const float* sk = ss + 32 + head * 4;
    float f0 = tempv / (fmaxf(sqrtf(sq[0]), 1e-12f) * fmaxf(sqrtf(sk[0]), 1e-12f));
    float f1 = tempv / (fmaxf(sqrtf(sq[1]), 1e-12f) * fmaxf(sqrtf(sk[1]), 1e-12f));
    float f2 = tempv / (fmaxf(sqrtf(sq[2]), 1e-12f) * fmaxf(sqrtf(sk[2]), 1e-12f));
    float f3 = tempv / (fmaxf(sqrtf(sq[3]), 1e-12f) * fmaxf(sqrtf(sk[3]), 1e-12f));
    float M = fabsf(tempv);   // |score| <= |temp| since |q^.k^| <= 1

    const float4* kb4 = (const float4*)kh + (head << 12);
    const float4* vb4 = (const float4*)vh + (head << 12);
    float4 qv[RT];
    #pragma unroll
    for (int r = 0; r < RT; ++r) {
        qv[r] = ((const float4*)qh)[(head << 12) + n0 + r];
        qv[r].x *= f0; qv[r].y *= f1; qv[r].z *= f2; qv[r].w *= f3;
    }

    __syncthreads();                               // (1) clears visible

    // Phase 1: scores -> keys in regs (4 rows), fused pass-0 histograms
    unsigned keys[RT * 16];
    #pragma unroll
    for (int j = 0; j < 16; ++j) {
        int m = tid + (j << 8);
        float4 kv = kb4[m];
        #pragma unroll
        for (int r = 0; r < RT; ++r) {
            float val = qv[r].x * kv.x;
            val = fmaf(qv[r].y, kv.y, val);
            val = fmaf(qv[r].z, kv.z, val);
            val = fmaf(qv[r].w, kv.w, val);
            unsigned key = key_of(val);
            keys[(r << 4) | j] = key;
            atomicAdd(&hist[0][r][key >> 24], 1u);
        }
    }

    unsigned need[RT], pre[RT];
    #pragma unroll
    for (int r = 0; r < RT; ++r) { need[r] = KK; pre[r] = 0; }

    #pragma unroll
    for (int pass = 0; pass < 4; ++pass) {
        __syncthreads();                           // (2..5) pass-p atomics done
        #pragma unroll
        for (int r = 0; r < RT; ++r) {
            // per-wave suffix scan of hist[pass][r] (redundant across waves)
            unsigned c0 = hist[pass][r][lane];
            unsigned c1 = hist[pass][r][64 + lane];
            unsigned c2 = hist[pass][r][128 + lane];
            unsigned c3 = hist[pass][r][192 + lane];
            unsigned s0 = c0, s1 = c1, s2 = c2, s3 = c3;
            #pragma unroll
            for (int off = 1; off < 64; off <<= 1) {
                unsigned v0 = __shfl_down(s0, off, 64);
                unsigned v1 = __shfl_down(s1, off, 64);
                unsigned v2 = __shfl_down(s2, off, 64);
                unsigned v3 = __shfl_down(s3, off, 64);
                if (lane + off < 64) { s0 += v0; s1 += v1; s2 += v2; s3 += v3; }
            }
            unsigned t1 = __shfl(s1, 0, 64), t2 = __shfl(s2, 0, 64), t3 = __shfl(s3, 0, 64);
            unsigned S0 = s0 + t1 + t2 + t3;
            unsigned S1 = s1 + t2 + t3;
            unsigned S2 = s2 + t3;
            unsigned S3 = s3;
            unsigned digL = 0, needL = 0;
            bool found = false;
            if (S0 >= need[r] && S0 - c0 < need[r]) { digL = lane;       needL = need[r] - (S0 - c0); found = true; }
            if (S1 >= need[r] && S1 - c1 < need[r]) { digL = 64 + lane;  needL = need[r] - (S1 - c1); found = true; }
            if (S2 >= need[r] && S2 - c2 < need[r]) { digL = 128 + lane; needL = need[r] - (S2 - c2); found = true; }
            if (S3 >= need[r] && S3 - c3 < need[r]) { digL = 192 + lane; needL = need[r] - (S3 - c3); found = true; }
            unsigned long long mk = __ballot(found);
            int src = __builtin_ctzll(mk);
            unsigned dig = __shfl((int)digL, src, 64);
            need[r] = __shfl((int)needL, src, 64);
            pre[r] = (pre[r] << 8) | dig;
        }
        // next-pass atomics (prefix compare)
        if (pass == 0) {
            #pragma unroll
            for (int j = 0; j < 16; ++j)
                #pragma unroll
                for (int r = 0; r < RT; ++r) {
                    unsigned k = keys[(r << 4) | j];
                    if ((k >> 24) == pre[r]) atomicAdd(&hist[1][r][(k >> 16) & 255u], 1u);
                }
        } else if (pass == 1) {
            #pragma unroll
            for (int j = 0; j < 16; ++j)
                #pragma unroll
                for (int r = 0; r < RT; ++r) {
                    unsigned k = keys[(r << 4) | j];
                    if ((k >> 16) == pre[r]) atomicAdd(&hist[2][r][(k >> 8) & 255u], 1u);
                }
        } else if (pass == 2) {
            #pragma unroll
            for (int j = 0; j < 16; ++j)
                #pragma unroll
                for (int r = 0; r < RT; ++r) {
                    unsigned k = keys[(r << 4) | j];
                    if ((k >> 8) == pre[r]) atomicAdd(&hist[3][r][k & 255u], 1u);
                }
        }
    }
    // pre[r] = tau (exact KK-th largest key), need[r] = tied entries to keep

    // count ties per row (block-wide), then fold scaleEq into phase 3
    unsigned cl[RT];
    #pragma unroll
    for (int r = 0; r < RT; ++r) cl[r] = 0;
    #pragma unroll
    for (int j = 0; j < 16; ++j)
        #pragma unroll
        for (int r = 0; r < RT; ++r)
            cl[r] += (keys[(r << 4) | j] == pre[r]) ? 1u : 0u;
    #pragma unroll
    for (int r = 0; r < RT; ++r) {
        #pragma unroll
        for (int off = 32; off > 0; off >>= 1) cl[r] += __shfl_down(cl[r], off, 64);
    }
    if (lane == 0) {
        #pragma unroll
        for (int r = 0; r < RT; ++r) cnt_red[wv][r] = cl[r];
    }
    __syncthreads();                               // (6)
    float se[RT];
    #pragma unroll
    for (int r = 0; r < RT; ++r) {
        unsigned tot = cnt_red[0][r] + cnt_red[1][r] + cnt_red[2][r] + cnt_red[3][r];
        se[r] = (float)need[r] / (float)tot;
    }

    // Phase 3: masked softmax + PV; V loaded once per element, shared by 4 rows
    float acc[RT][5];
    #pragma unroll
    for (int r = 0; r < RT; ++r)
        #pragma unroll
        for (int c = 0; c < 5; ++c) acc[r][c] = 0.f;
    #pragma unroll
    for (int j = 0; j < 16; ++j) {
        int m = tid + (j << 8);
        float4 vv = vb4[m];
        #pragma unroll
        for (int r = 0; r < RT; ++r) {
            unsigned k = keys[(r << 4) | j];
            if (k >= pre[r]) {
                float w = __expf(float_of_key(k) - M);
                if (k == pre[r]) w *= se[r];
                acc[r][0] += w;
                acc[r][1] = fmaf(w, vv.x, acc[r][1]);
                acc[r][2] = fmaf(w, vv.y, acc[r][2]);
                acc[r][3] = fmaf(w, vv.z, acc[r][3]);
                acc[r][4] = fmaf(w, vv.w, acc[r][4]);
            }
        }
    }
    #pragma unroll
    for (int r = 0; r < RT; ++r)
        #pragma unroll
        for (int c = 0; c < 5; ++c) {
            #pragma unroll
            for (int off = 32; off > 0; off >>= 1)
                acc[r][c] += __shfl_down(acc[r][c], off, 64);
        }
    if (lane == 0) {
        #pragma unroll
        for (int r = 0; r < RT; ++r)
            #pragma unroll
            for (int c = 0; c < 5; ++c) red[wv][r][c] = acc[r][c];
    }
    __syncthreads();                               // (7)
    if (tid < RT) {
        int r = tid;
        float D = 0, o0 = 0, o1 = 0, o2 = 0, o3 = 0;
        #pragma unroll
        for (int w = 0; w < 4; ++w) {
            D += red[w][r][0];
            o0 += red[w][r][1]; o1 += red[w][r][2];
            o2 += red[w][r][3]; o3 += red[w][r][4];
        }
        float invD = 1.f / D;
        int n = n0 + r;
        outp[((head << 2) + 0) * NTOK + n] = o0 * invD;
        outp[((head << 2) + 1) * NTOK + n] = o1 * invD;
        outp[((head << 2) + 2) * NTOK + n] = o2 * invD;
        outp[((head << 2) + 3) * NTOK + n] = o3 * invD;
    }
}

// out[o][p] = sum_ch wp[o][ch] * ao[head(ch)*4+cph(ch)][p*4 + t(ch)], ch = t*32 + head*4 + cph
__global__ void k_proj(const float* __restrict__ ao, const float* __restrict__ wp,
                       float* __restrict__ out) {
    __shared__ float chin[128];
    int p = blockIdx.x;
    int tid = threadIdx.x;       // 128
    int t = tid >> 5;
    int c = tid & 31;
    chin[tid] = ao[c * NTOK + (p << 2) + t];
    __syncthreads();
    const float* wr = wp + tid * 128;
    float acc = 0.f;
    #pragma unroll 8
    for (int ch = 0; ch < 128; ++ch) acc = fmaf(wr[ch], chin[ch], acc);
    out[tid * 1024 + p] = acc;
}

extern "C" void kernel_launch(void* const* d_in, const int* in_sizes, int n_in,
                              void* d_out, int out_size, void* d_ws, size_t ws_size,
                              hipStream_t stream) {
    const float* x    = (const float*)d_in[0];
    const float* temp = (const float*)d_in[1];
    const float* wq   = (const float*)d_in[2];
    const float* wdw  = (const float*)d_in[3];
    const float* wp   = (const float*)d_in[4];
    float* out = (float*)d_out;
    float* ws = (float*)d_ws;

    float* qh = ws;                      // [head][n][4] = 131072 floats
    float* kh = qh + 131072;
    float* vh = kh + 131072;
    float* ao = vh + 131072;             // [c][n]
    float* ssb = ao + 131072;            // 64 floats

    hipMemsetAsync(ssb, 0, 64 * sizeof(float), stream);
    k_fused<<<384,  256, 0, stream>>>(x, wq, wdw, qh, kh, vh, ssb);
    k_attn <<<8192, 256, 0, stream>>>(qh, kh, vh, ssb, temp, ao);
    k_proj <<<1024, 128, 0, stream>>>(ao, wp, out);
}

// Round 5
// 448.771 us; speedup vs baseline: 1.1384x; 1.0831x over previous
//
#include <hip/hip_runtime.h>

#define NTOK 4096
#define KK   3276   // int(4096 * 0.8)

typedef unsigned u32x16 __attribute__((ext_vector_type(16)));

__device__ __forceinline__ unsigned key_of(float f) {
    unsigned u = __float_as_uint(f);
    return (u & 0x80000000u) ? ~u : (u | 0x80000000u);
}
__device__ __forceinline__ float float_of_key(unsigned k) {
    unsigned u = (k & 0x80000000u) ? (k ^ 0x80000000u) : ~k;
    return __uint_as_float(u);
}

// suffix-scan 256 bins (4 chunks of 64 held by lanes) and pick digit where
// descending cumulative count crosses `need`; update need and prefix.
__device__ __forceinline__ void scan_pick(unsigned c0, unsigned c1, unsigned c2, unsigned c3,
                                          int lane, unsigned& need, unsigned& pre) {
    unsigned s0 = c0, s1 = c1, s2 = c2, s3 = c3;
    #pragma unroll
    for (int off = 1; off < 64; off <<= 1) {
        unsigned v0 = __shfl_down(s0, off, 64);
        unsigned v1 = __shfl_down(s1, off, 64);
        unsigned v2 = __shfl_down(s2, off, 64);
        unsigned v3 = __shfl_down(s3, off, 64);
        if (lane + off < 64) { s0 += v0; s1 += v1; s2 += v2; s3 += v3; }
    }
    unsigned t1 = __shfl(s1, 0, 64), t2 = __shfl(s2, 0, 64), t3 = __shfl(s3, 0, 64);
    unsigned S0 = s0 + t1 + t2 + t3;
    unsigned S1 = s1 + t2 + t3;
    unsigned S2 = s2 + t3;
    unsigned S3 = s3;
    unsigned digL = 0, needL = 0;
    bool found = false;
    if (S0 >= need && S0 - c0 < need) { digL = lane;       needL = need - (S0 - c0); found = true; }
    if (S1 >= need && S1 - c1 < need) { digL = 64 + lane;  needL = need - (S1 - c1); found = true; }
    if (S2 >= need && S2 - c2 < need) { digL = 128 + lane; needL = need - (S2 - c2); found = true; }
    if (S3 >= need && S3 - c3 < need) { digL = 192 + lane; needL = need - (S3 - c3); found = true; }
    unsigned long long mk = __ballot(found);
    int src = __builtin_ctzll(mk);
    unsigned dig = __shfl((int)digL, src, 64);
    need = __shfl((int)needL, src, 64);
    pre = (pre << 8) | dig;
}

// Fused: pointwise-over-t conv + depthwise 3x3 + scatter to [head][n][4] + sum-of-squares
__global__ __launch_bounds__(256) void k_fused(const float* __restrict__ x,
                                               const float* __restrict__ wq,
                                               const float* __restrict__ wdw,
                                               float* __restrict__ qh,
                                               float* __restrict__ kh,
                                               float* __restrict__ vh,
                                               float* __restrict__ ss) {
    __shared__ float p[1024];
    int b = blockIdx.x;
    int o = b >> 5, c = b & 31;
    int tid = threadIdx.x;
    float w0 = wq[o * 4 + 0], w1 = wq[o * 4 + 1], w2 = wq[o * 4 + 2], w3 = wq[o * 4 + 3];
    const float* x0 = x + (c << 10);
    #pragma unroll
    for (int r = 0; r < 4; ++r) {
        int hw = tid + (r << 8);
        float a = w0 * x0[hw];
        a = fmaf(w1, x0[(32 << 10) + hw], a);
        a = fmaf(w2, x0[(64 << 10) + hw], a);
        a = fmaf(w3, x0[(96 << 10) + hw], a);
        p[hw] = a;
    }
    __syncthreads();
    float wd[9];
    #pragma unroll
    for (int i = 0; i < 9; ++i) wd[i] = wdw[o * 9 + i];
    int g = o >> 2, t = o & 3;
    int head = c >> 2, cph = c & 3;
    float* dst = (g == 0) ? qh : (g == 1) ? kh : vh;
    float ssum = 0.f;
    #pragma unroll
    for (int r = 0; r < 4; ++r) {
        int hw = tid + (r << 8);
        int wcol = hw & 31, hrow = hw >> 5;
        float a = 0.f;
        #pragma unroll
        for (int dy = -1; dy <= 1; ++dy) {
            int hh = hrow + dy;
            if (hh < 0 || hh > 31) continue;
            #pragma unroll
            for (int dx = -1; dx <= 1; ++dx) {
                int ww = wcol + dx;
                if (ww < 0 || ww > 31) continue;
                a = fmaf(wd[(dy + 1) * 3 + (dx + 1)], p[hh * 32 + ww], a);
            }
        }
        int n = (hw << 2) + t;
        dst[(((head << 12) + n) << 2) + cph] = a;
        ssum = fmaf(a, a, ssum);
    }
    if (g < 2) {
        #pragma unroll
        for (int off = 32; off > 0; off >>= 1) ssum += __shfl_down(ssum, off, 64);
        if ((tid & 63) == 0) atomicAdd(&ss[g * 32 + c], ssum);
    }
}

// One block per (head, 2 consecutive rows). Keys in two ext_vector SSA values.
__global__ __launch_bounds__(256, 4) void k_attn(const float* __restrict__ qh,
                                                 const float* __restrict__ kh,
                                                 const float* __restrict__ vh,
                                                 const float* __restrict__ ss,
                                                 const float* __restrict__ temp,
                                                 float* __restrict__ outp) {
    __shared__ __align__(16) unsigned h0[2][256][4];   // pass-0: 4 bank-interleaved copies
    __shared__ unsigned h123[3][2][256];               // passes 1-3: single copy
    __shared__ float red[4][10];
    __shared__ unsigned cnt_red[4][2];

    int bid = blockIdx.x;
    int head = bid >> 11;
    int n0 = (bid & 2047) << 1;
    int tid = threadIdx.x;
    int lane = tid & 63;
    int wv = tid >> 6;
    int cp = (tid >> 4) & 3;          // histogram copy index (16 lanes per copy)

    // clear histograms: 2048 + 1536 words
    unsigned* hb = &h0[0][0][0];
    #pragma unroll
    for (int i = 0; i < 8; ++i) hb[tid + (i << 8)] = 0;
    unsigned* hc = &h123[0][0][0];
    #pragma unroll
    for (int i = 0; i < 6; ++i) hc[tid + (i << 8)] = 0;

    // per-cph combined scale (uniform across block)
    float tempv = temp[head];
    const float* sq = ss + head * 4;
    const float* sk = ss + 32 + head * 4;
    float f0 = tempv / (fmaxf(sqrtf(sq[0]), 1e-12f) * fmaxf(sqrtf(sk[0]), 1e-12f));
    float f1 = tempv / (fmaxf(sqrtf(sq[1]), 1e-12f) * fmaxf(sqrtf(sk[1]), 1e-12f));
    float f2 = tempv / (fmaxf(sqrtf(sq[2]), 1e-12f) * fmaxf(sqrtf(sk[2]), 1e-12f));
    float f3 = tempv / (fmaxf(sqrtf(sq[3]), 1e-12f) * fmaxf(sqrtf(sk[3]), 1e-12f));
    float M = fabsf(tempv);           // |score| <= |temp| since |q^.k^| <= 1

    const float4* kb4 = (const float4*)kh + (head << 12);
    const float4* vb4 = (const float4*)vh + (head << 12);
    float4 qa = ((const float4*)qh)[(head << 12) + n0];
    float4 qb = ((const float4*)qh)[(head << 12) + n0 + 1];
    qa.x *= f0; qa.y *= f1; qa.z *= f2; qa.w *= f3;
    qb.x *= f0; qb.y *= f1; qb.z *= f2; qb.w *= f3;

    __syncthreads();                                    // B1: clears visible

    // Phase 1: scores -> keys (SSA vectors), pass-0 histograms (4-copy)
    u32x16 k0, k1;
    #pragma unroll
    for (int j = 0; j < 16; ++j) {
        int m = tid + (j << 8);
        float4 kv = kb4[m];
        float va = qa.x * kv.x;
        va = fmaf(qa.y, kv.y, va);
        va = fmaf(qa.z, kv.z, va);
        va = fmaf(qa.w, kv.w, va);
        float vb = qb.x * kv.x;
        vb = fmaf(qb.y, kv.y, vb);
        vb = fmaf(qb.z, kv.z, vb);
        vb = fmaf(qb.w, kv.w, vb);
        unsigned ka = key_of(va), kb = key_of(vb);
        k0[j] = ka; k1[j] = kb;
        atomicAdd(&h0[0][ka >> 24][cp], 1u);
        atomicAdd(&h0[1][kb >> 24][cp], 1u);
    }
    __syncthreads();                                    // B2: pass-0 atomics done

    unsigned need0 = KK, need1 = KK, pre0 = 0, pre1 = 0;
    // scan pass-0 (merge 4 copies via uint4 reads), redundant in each wave
    {
        uint4 a0 = *(const uint4*)&h0[0][lane][0];
        uint4 a1 = *(const uint4*)&h0[0][64 + lane][0];
        uint4 a2 = *(const uint4*)&h0[0][128 + lane][0];
        uint4 a3 = *(const uint4*)&h0[0][192 + lane][0];
        scan_pick(a0.x + a0.y + a0.z + a0.w, a1.x + a1.y + a1.z + a1.w,
                  a2.x + a2.y + a2.z + a2.w, a3.x + a3.y + a3.z + a3.w, lane, need0, pre0);
        uint4 b0 = *(const uint4*)&h0[1][lane][0];
        uint4 b1 = *(const uint4*)&h0[1][64 + lane][0];
        uint4 b2 = *(const uint4*)&h0[1][128 + lane][0];
        uint4 b3 = *(const uint4*)&h0[1][192 + lane][0];
        scan_pick(b0.x + b0.y + b0.z + b0.w, b1.x + b1.y + b1.z + b1.w,
                  b2.x + b2.y + b2.z + b2.w, b3.x + b3.y + b3.z + b3.w, lane, need1, pre1);
    }
    // pass-1 atomics
    #pragma unroll
    for (int j = 0; j < 16; ++j) {
        if ((k0[j] >> 24) == pre0) atomicAdd(&h123[0][0][(k0[j] >> 16) & 255u], 1u);
        if ((k1[j] >> 24) == pre1) atomicAdd(&h123[0][1][(k1[j] >> 16) & 255u], 1u);
    }
    __syncthreads();                                    // B3
    scan_pick(h123[0][0][lane], h123[0][0][64 + lane], h123[0][0][128 + lane],
              h123[0][0][192 + lane], lane, need0, pre0);
    scan_pick(h123[0][1][lane], h123[0][1][64 + lane], h123[0][1][128 + lane],
              h123[0][1][192 + lane], lane, need1, pre1);
    // pass-2 atomics
    #pragma unroll
    for (int j = 0; j < 16; ++j) {
        if ((k0[j] >> 16) == pre0) atomicAdd(&h123[1][0][(k0[j] >> 8) & 255u], 1u);
        if ((k1[j] >> 16) == pre1) atomicAdd(&h123[1][1][(k1[j] >> 8) & 255u], 1u);
    }
    __syncthreads();                                    // B4
    scan_pick(h123[1][0][lane], h123[1][0][64 + lane], h123[1][0][128 + lane],
              h123[1][0][192 + lane], lane, need0, pre0);
    scan_pick(h123[1][1][lane], h123[1][1][64 + lane], h123[1][1][128 + lane],
              h123[1][1][192 + lane], lane, need1, pre1);
    // pass-3 atomics
    #pragma unroll
    for (int j = 0; j < 16; ++j) {
        if ((k0[j] >> 8) == pre0) atomicAdd(&h123[2][0][k0[j] & 255u], 1u);
        if ((k1[j] >> 8) == pre1) atomicAdd(&h123[2][1][k1[j] & 255u], 1u);
    }
    __syncthreads();                                    // B5
    scan_pick(h123[2][0][lane], h123[2][0][64 + lane], h123[2][0][128 + lane],
              h123[2][0][192 + lane], lane, need0, pre0);
    scan_pick(h123[2][1][lane], h123[2][1][64 + lane], h123[2][1][128 + lane],
              h123[2][1][192 + lane], lane, need1, pre1);
    // pre = tau (exact KK-th largest key), need = tied entries kept

    // tie count per row
    unsigned cl0 = 0, cl1 = 0;
    #pragma unroll
    for (int j = 0; j < 16; ++j) {
        cl0 += (k0[j] == pre0) ? 1u : 0u;
        cl1 += (k1[j] == pre1) ? 1u : 0u;
    }
    #pragma unroll
    for (int off = 32; off > 0; off >>= 1) {
        cl0 += __shfl_down(cl0, off, 64);
        cl1 += __shfl_down(cl1, off, 64);
    }
    if (lane == 0) { cnt_red[wv][0] = cl0; cnt_red[wv][1] = cl1; }
    __syncthreads();                                    // B6
    float se0 = (float)need0 / (float)(cnt_red[0][0] + cnt_red[1][0] + cnt_red[2][0] + cnt_red[3][0]);
    float se1 = (float)need1 / (float)(cnt_red[0][1] + cnt_red[1][1] + cnt_red[2][1] + cnt_red[3][1]);

    // Phase 3: masked softmax + PV; V loaded once, shared by both rows
    float d0 = 0.f, d1 = 0.f;
    float4 A = {0.f, 0.f, 0.f, 0.f}, B = {0.f, 0.f, 0.f, 0.f};
    #pragma unroll
    for (int j = 0; j < 16; ++j) {
        int m = tid + (j << 8);
        float4 vv = vb4[m];
        unsigned ka = k0[j];
        if (ka >= pre0) {
            float w = __expf(float_of_key(ka) - M);
            if (ka == pre0) w *= se0;
            d0 += w;
            A.x = fmaf(w, vv.x, A.x); A.y = fmaf(w, vv.y, A.y);
            A.z = fmaf(w, vv.z, A.z); A.w = fmaf(w, vv.w, A.w);
        }
        unsigned kb = k1[j];
        if (kb >= pre1) {
            float w = __expf(float_of_key(kb) - M);
            if (kb == pre1) w *= se1;
            d1 += w;
            B.x = fmaf(w, vv.x, B.x); B.y = fmaf(w, vv.y, B.y);
            B.z = fmaf(w, vv.z, B.z); B.w = fmaf(w, vv.w, B.w);
        }
    }
    #pragma unroll
    for (int off = 32; off > 0; off >>= 1) {
        d0 += __shfl_down(d0, off, 64);
        A.x += __shfl_down(A.x, off, 64); A.y += __shfl_down(A.y, off, 64);
        A.z += __shfl_down(A.z, off, 64); A.w += __shfl_down(A.w, off, 64);
        d1 += __shfl_down(d1, off, 64);
        B.x += __shfl_down(B.x, off, 64); B.y += __shfl_down(B.y, off, 64);
        B.z += __shfl_down(B.z, off, 64); B.w += __shfl_down(B.w, off, 64);
    }
    if (lane == 0) {
        float* r = red[wv];
        r[0] = d0; r[1] = A.x; r[2] = A.y; r[3] = A.z; r[4] = A.w;
        r[5] = d1; r[6] = B.x; r[7] = B.y; r[8] = B.z; r[9] = B.w;
    }
    __syncthreads();                                    // B7
    if (tid < 2) {
        int base = tid * 5;
        float D = red[0][base] + red[1][base] + red[2][base] + red[3][base];
        float o0 = red[0][base + 1] + red[1][base + 1] + red[2][base + 1] + red[3][base + 1];
        float o1 = red[0][base + 2] + red[1][base + 2] + red[2][base + 2] + red[3][base + 2];
        float o2 = red[0][base + 3] + red[1][base + 3] + red[2][base + 3] + red[3][base + 3];
        float o3 = red[0][base + 4] + red[1][base + 4] + red[2][base + 4] + red[3][base + 4];
        float invD = 1.f / D;
        int n = n0 + tid;
        outp[((head << 2) + 0) * NTOK + n] = o0 * invD;
        outp[((head << 2) + 1) * NTOK + n] = o1 * invD;
        outp[((head << 2) + 2) * NTOK + n] = o2 * invD;
        outp[((head << 2) + 3) * NTOK + n] = o3 * invD;
    }
}

// out[o][p] = sum_ch wp[o][ch] * ao[head(ch)*4+cph(ch)][p*4 + t(ch)], ch = t*32 + head*4 + cph
__global__ void k_proj(const float* __restrict__ ao, const float* __restrict__ wp,
                       float* __restrict__ out) {
    __shared__ float chin[128];
    int p = blockIdx.x;
    int tid = threadIdx.x;       // 128
    int t = tid >> 5;
    int c = tid & 31;
    chin[tid] = ao[c * NTOK + (p << 2) + t];
    __syncthreads();
    const float* wr = wp + tid * 128;
    float acc = 0.f;
    #pragma unroll 8
    for (int ch = 0; ch < 128; ++ch) acc = fmaf(wr[ch], chin[ch], acc);
    out[tid * 1024 + p] = acc;
}

extern "C" void kernel_launch(void* const* d_in, const int* in_sizes, int n_in,
                              void* d_out, int out_size, void* d_ws, size_t ws_size,
                              hipStream_t stream) {
    const float* x    = (const float*)d_in[0];
    const float* temp = (const float*)d_in[1];
    const float* wq   = (const float*)d_in[2];
    const float* wdw  = (const float*)d_in[3];
    const float* wp   = (const float*)d_in[4];
    float* out = (float*)d_out;
    float* ws = (float*)d_ws;

    float* qh = ws;                      // [head][n][4] = 131072 floats
    float* kh = qh + 131072;
    float* vh = kh + 131072;
    float* ao = vh + 131072;             // [c][n]
    float* ssb = ao + 131072;            // 64 floats

    hipMemsetAsync(ssb, 0, 64 * sizeof(float), stream);
    k_fused<<<384,   256, 0, stream>>>(x, wq, wdw, qh, kh, vh, ssb);
    k_attn <<<16384, 256, 0, stream>>>(qh, kh, vh, ssb, temp, ao);
    k_proj <<<1024,  128, 0, stream>>>(ao, wp, out);
}